// Round 10
// baseline (148.417 us; speedup 1.0000x reference)
//
#include <hip/hip_runtime.h>
#include <hip/hip_bf16.h>
#include <stdint.h>

#define DEV __device__ __forceinline__

typedef unsigned short u16;
typedef unsigned char u8;
typedef __attribute__((ext_vector_type(8))) short bf16x8;        // 8 bf16 MFMA A/B frag
typedef __attribute__((ext_vector_type(4))) float f32x4;         // MFMA C/D frag
typedef __attribute__((ext_vector_type(4))) int i32x4;           // i8 MFMA frag / acc

DEV u16 bf(float v) {
  __hip_bfloat16 h = __float2bfloat16(v);
  union { __hip_bfloat16 h; u16 u; } x; x.h = h;
  return x.u;
}

// sigmoid(v/sqrt(512)) = 1/(1+exp2(v * -log2(e)/sqrt(512)))
DEV float sigmoid_s(float v) {
  float e = __builtin_amdgcn_exp2f(v * -0.0637587143f);
  return __builtin_amdgcn_rcpf(1.0f + e);
}

DEV void gld_lds(const void* g, void* l) {
  __builtin_amdgcn_global_load_lds(
      (const __attribute__((address_space(1))) uint32_t*)g,
      (__attribute__((address_space(3))) uint32_t*)l, 16, 0, 0);
}

// ---------------- f32 -> bf16 conversion (x, Wq, Wv) ----------------
__global__ void conv_kernel(const float* __restrict__ x,
                            const float* __restrict__ Wq,
                            const float* __restrict__ Wv,
                            u16* __restrict__ xb,
                            u16* __restrict__ wqb,
                            u16* __restrict__ wvb) {
  const int NX4 = (16384 * 512) / 4;
  const int NW4 = (512 * 512) / 4;
  int i = blockIdx.x * blockDim.x + threadIdx.x;
  const float4* src; u16* dst; int off;
  if (i < NX4)            { src = (const float4*)x;  dst = xb;  off = i; }
  else if (i < NX4 + NW4) { src = (const float4*)Wq; dst = wqb; off = i - NX4; }
  else                    { src = (const float4*)Wv; dst = wvb; off = i - NX4 - NW4; }
  float4 f = src[off];
  ushort4 o = make_ushort4(bf(f.x), bf(f.y), bf(f.z), bf(f.w));
  ((ushort4*)dst)[off] = o;
}

// ---------------- projection GEMM (bf16 in, i8 out), 2-phase dbuf ----------
// C[m][n] = sum_k A[m][k]*B[n][k].  T1 XCD swizzle; T2 LDS XOR swizzle.
// EPI: 4 = +bias[row] -> i8 | 5 = +bias[col] -> i8   (scale 127/4)
template <int EPI, int BM, int BN, int NW, int NBN, int NBM>
__global__ __launch_bounds__(NW * 64, 2)
void gemm_nt(const u16* __restrict__ A, int lda,
             const u16* __restrict__ B, int ldb,
             signed char* __restrict__ C8, int ldc,
             const float* __restrict__ bias, int K) {
  constexpr int BK   = 64;
  constexpr int WC   = NW / 2;
  constexpr int MREP = BM / 32;
  constexpr int NREP = BN / (16 * WC);
  constexpr int CPW  = (BM + BN) / (8 * NW);
  constexpr int TILE = (BM + BN) * BK;
  __shared__ u16 lds[2 * TILE];

  const int tid  = threadIdx.x;
  const int lane = tid & 63;
  const int w    = tid >> 6;
  const int wr   = w / WC, wc = w % WC;

  const int nwg = (int)gridDim.x;
  const int id  = blockIdx.x;
  const int swz = (id & 7) * (nwg >> 3) + (id >> 3);
  const int bn  = swz % NBN;
  const int bm  = (swz / NBN) % NBM;

  const int lrow = lane & 15;
  const int rx   = lane & 7;
  const int srow = lane >> 3;
  const int scol = ((lane & 7) ^ srow) << 3;

  const u16* srcs[CPW];
#pragma unroll
  for (int c = 0; c < CPW; ++c) {
    int row = (w * CPW + c) * 8 + srow;
    srcs[c] = (row < BM)
        ? A + (long)(bm * BM + row) * lda + scol
        : B + (long)(bn * BN + (row - BM)) * ldb + scol;
  }

  f32x4 acc[MREP][NREP] = {};

  const int nk = K / BK;
#pragma unroll
  for (int c = 0; c < CPW; ++c)
    gld_lds(srcs[c], &lds[(w * CPW + c) * 512]);

  int p = 0;
  for (int kt = 0; kt < nk; ++kt) {
    if (kt + 1 < nk) {
#pragma unroll
      for (int c = 0; c < CPW; ++c)
        gld_lds(srcs[c] + (kt + 1) * BK, &lds[(p ^ 1) * TILE + (w * CPW + c) * 512]);
      asm volatile("s_waitcnt vmcnt(%0)" :: "i"(CPW) : "memory");
    } else {
      asm volatile("s_waitcnt vmcnt(0)" ::: "memory");
    }
    __builtin_amdgcn_s_barrier();
    asm volatile("" ::: "memory");

    const u16* Alds = &lds[p * TILE];
    const u16* Blds = &lds[p * TILE + BM * BK];
#pragma unroll
    for (int ks = 0; ks < 2; ++ks) {
      const int sl = ((ks * 4 + (lane >> 4)) ^ rx) << 3;
      bf16x8 af[MREP], bfr[NREP];
#pragma unroll
      for (int t = 0; t < MREP; ++t)
        af[t]  = *(const bf16x8*)&Alds[(wr * (BM / 2) + t * 16 + lrow) * BK + sl];
#pragma unroll
      for (int t = 0; t < NREP; ++t)
        bfr[t] = *(const bf16x8*)&Blds[(wc * (BN / WC) + t * 16 + lrow) * BK + sl];
#pragma unroll
      for (int mt = 0; mt < MREP; ++mt)
#pragma unroll
        for (int nt = 0; nt < NREP; ++nt)
          acc[mt][nt] = __builtin_amdgcn_mfma_f32_16x16x32_bf16(af[mt], bfr[nt], acc[mt][nt], 0, 0, 0);
    }

    asm volatile("" ::: "memory");
    __builtin_amdgcn_s_barrier();
    p ^= 1;
  }

  const int row0 = bm * BM + wr * (BM / 2);
  const int col0 = bn * BN + wc * (BN / WC);
  const int rsub = (lane >> 4) << 2;

#pragma unroll
  for (int mt = 0; mt < MREP; ++mt)
#pragma unroll
    for (int nt = 0; nt < NREP; ++nt)
#pragma unroll
      for (int r = 0; r < 4; ++r) {
        int row = row0 + mt * 16 + rsub + r;
        int col = col0 + nt * 16 + lrow;
        float v = acc[mt][nt][r] + ((EPI == 4) ? bias[row] : bias[col]);
        float t = fminf(fmaxf(v * 31.75f, -127.f), 127.f);
        C8[(long)row * ldc + col] = (signed char)(int)rintf(t);
      }
}

// ---------------- symmetric sigmoid(QQ^T) i8 GEMM -> u8 P, bn>=bm ----------
// 32 KB single-buffered staging; now 4 blocks/CU (16 waves) so the
// TRANS-heavy sigmoid epilogue and L2->LDS staging latency overlap across
// blocks. Epilogue: dequant -> sigmoid -> u8, LDS bounce (144 B stride),
// dual-orientation store for off-diagonal tiles.
template <int NB>
__global__ __launch_bounds__(256, 4)
void gemm_sym_sig_i8(const signed char* __restrict__ Q, long sQz,
                     u8* __restrict__ P, long sPz) {
  constexpr int TRI  = NB * (NB + 1) / 2;
  constexpr int LSTR = 144;                 // bounce byte stride (multiple of 16)
  __shared__ u8 lds[256 * 128];             // 32 KB staging; bounce overlays 128*144

  const int tid  = threadIdx.x;
  const int lane = tid & 63;
  const int w    = tid >> 6;
  const int wr   = w >> 1, wc = w & 1;

  const int nwg = (int)gridDim.x;
  const int id  = blockIdx.x;
  const int swz = (id & 7) * (nwg >> 3) + (id >> 3);
  const int z   = swz / TRI;
  int rem = swz % TRI;
  int bm = 0;
  while (rem >= NB - bm) { rem -= NB - bm; ++bm; }
  const int bn = bm + rem;

  const signed char* Qz = Q + (long)z * sQz;

  const int lrow = lane & 15;
  const int rx   = lane & 7;
  const int srow = lane >> 3;                     // row within 8-row chunk
  const int scol = ((lane & 7) ^ srow) << 4;      // pre-swizzled 16B slot (of 8)

  const signed char* srcs[8];
#pragma unroll
  for (int c = 0; c < 8; ++c) {
    int row = (w * 8 + c) * 8 + srow;             // 0..255
    srcs[c] = (row < 128)
        ? Qz + (long)(bm * 128 + row) * 512 + scol
        : Qz + (long)(bn * 128 + (row - 128)) * 512 + scol;
  }

  i32x4 acc[4][4] = {};

  for (int kt = 0; kt < 4; ++kt) {                // BK = 128 bytes
#pragma unroll
    for (int c = 0; c < 8; ++c)
      gld_lds(srcs[c] + kt * 128, &lds[(w * 8 + c) * 1024]);
    __syncthreads();

#pragma unroll
    for (int ks = 0; ks < 2; ++ks) {              // two 64B k-slices
      const int sl = ((ks * 4 + (lane >> 4)) ^ rx) << 4;
      i32x4 af[4], bfv[4];
#pragma unroll
      for (int t = 0; t < 4; ++t) {
        af[t]  = *(const i32x4*)&lds[(wr * 64 + t * 16 + lrow) * 128 + sl];
        bfv[t] = *(const i32x4*)&lds[128 * 128 + (wc * 64 + t * 16 + lrow) * 128 + sl];
      }
#pragma unroll
      for (int mt = 0; mt < 4; ++mt)
#pragma unroll
        for (int nt = 0; nt < 4; ++nt)
          acc[mt][nt] = __builtin_amdgcn_mfma_i32_16x16x64_i8(af[mt], bfv[nt], acc[mt][nt], 0, 0, 0);
    }
    __syncthreads();
  }

  u8* Pz = P + (long)z * sPz;
  const int rsub = (lane >> 4) << 2;
  const bool offdiag = (bn != bm);

  // dequant (4/127)^2 -> sigmoid -> u8 0..127
  u8 sb[4][4][4];
#pragma unroll
  for (int mt = 0; mt < 4; ++mt)
#pragma unroll
    for (int nt = 0; nt < 4; ++nt)
#pragma unroll
      for (int r = 0; r < 4; ++r) {
        float v = (float)acc[mt][nt][r] * 9.91941e-4f;
        sb[mt][nt][r] = (u8)(int)(sigmoid_s(v) * 127.f + 0.5f);
      }

  const int rl = wr * 64 + rsub;    // local row base (+mt*16, +r)
  const int cl = wc * 64 + lrow;    // local col base (+nt*16)
  const int coloff = (tid & 7) * 16;
  const int rdrow  = tid >> 3;      // 0..31

  // pass 1: normal orientation bounce -> dense 16B stores
#pragma unroll
  for (int mt = 0; mt < 4; ++mt)
#pragma unroll
    for (int nt = 0; nt < 4; ++nt)
#pragma unroll
      for (int r = 0; r < 4; ++r)
        lds[(rl + mt * 16 + r) * LSTR + cl + nt * 16] = sb[mt][nt][r];
  __syncthreads();
#pragma unroll
  for (int j = 0; j < 4; ++j) {
    int row = j * 32 + rdrow;
    uint4 v = *(const uint4*)&lds[row * LSTR + coloff];
    *(uint4*)&Pz[(long)(bm * 128 + row) * 4096 + bn * 128 + coloff] = v;
  }

  if (offdiag) {
    __syncthreads();   // WAR: pass-1 reads done before overwrite
    // pass 2: transposed; frag's 4 consecutive rows -> 4 bytes -> one u32
#pragma unroll
    for (int mt = 0; mt < 4; ++mt)
#pragma unroll
      for (int nt = 0; nt < 4; ++nt) {
        uint32_t pk = (uint32_t)sb[mt][nt][0] | ((uint32_t)sb[mt][nt][1] << 8) |
                      ((uint32_t)sb[mt][nt][2] << 16) | ((uint32_t)sb[mt][nt][3] << 24);
        *(uint32_t*)&lds[(cl + nt * 16) * LSTR + rl + mt * 16] = pk;
      }
    __syncthreads();
#pragma unroll
    for (int j = 0; j < 4; ++j) {
      int row = j * 32 + rdrow;
      uint4 v = *(const uint4*)&lds[row * LSTR + coloff];
      *(uint4*)&Pz[(long)(bn * 128 + row) * 4096 + bm * 128 + coloff] = v;
    }
  }
}

// ---------------- O = (SP*SV) * P_u8 @ vT_i8^T, i8 MFMA, 2-phase dbuf ------
// 64x128 tile, 4 waves (2x2), wave tile 32x64. Grid 1024 = 4 blocks/CU at
// launch_bounds(256,4) -> 16 waves/CU (was 8): TLP test vs the LDS-traffic
// hypothesis (this layout has 1.5x LDS reads/FLOP but 2x waves).
__global__ __launch_bounds__(256, 4)
void gemm_pv_i8(const signed char* __restrict__ A,   // P [4*4096][4096] (u8 vals)
                const signed char* __restrict__ B,   // vT_i8 [512][16384]
                float* __restrict__ C, int K) {      // out [4*4096][512]
  constexpr int NBN = 4, NBM = 64;
  constexpr int TILE = 192 * 64;          // bytes per buffer (12 KB)
  __shared__ signed char lds[2 * TILE];   // 24 KB

  const int tid  = threadIdx.x;
  const int lane = tid & 63;
  const int w    = tid >> 6;              // 0..3
  const int wr   = w >> 1, wc = w & 1;

  const int nwg = (int)gridDim.x;
  const int id  = blockIdx.x;
  const int swz = (id & 7) * (nwg >> 3) + (id >> 3);
  const int bn  = swz % NBN;
  const int t0  = swz / NBN;
  const int bm  = t0 % NBM;
  const int z   = t0 / NBM;

  const signed char* Az = A + (long)z * 4096 * 4096;
  const signed char* Bz = B + (long)z * 4096;
  float* Cz = C + (long)z * 4096 * 512;

  const int lrow = lane & 15;
  const int kq   = ((lane >> 4) ^ ((lrow >> 1) & 3)) << 4;   // read slot byte-off

  // staging: 12 chunks x 1KB (16 rows x 64 B); 3 chunks/wave
  const signed char* srcs[3];
#pragma unroll
  for (int c = 0; c < 3; ++c) {
    int ci = w * 3 + c;
    int r  = ci * 16 + (lane >> 2);            // tile row 0..191 (A:0-63 | B:64-191)
    int sl = (lane & 3) ^ ((r >> 1) & 3);      // pre-swizzled source slot
    srcs[c] = (r < 64)
        ? Az + (long)(bm * 64 + r) * 4096 + sl * 16
        : Bz + (long)(bn * 128 + (r - 64)) * 16384 + sl * 16;
  }

  i32x4 acc[2][4] = {};

  const int nk = K >> 6;   // 64
#pragma unroll
  for (int c = 0; c < 3; ++c)
    gld_lds(srcs[c], &lds[(w * 3 + c) * 1024]);

  int p = 0;
  for (int kt = 0; kt < nk; ++kt) {
    if (kt + 1 < nk) {
#pragma unroll
      for (int c = 0; c < 3; ++c)
        gld_lds(srcs[c] + (kt + 1) * 64, &lds[(p ^ 1) * TILE + (w * 3 + c) * 1024]);
      asm volatile("s_waitcnt vmcnt(3)" ::: "memory");
    } else {
      asm volatile("s_waitcnt vmcnt(0)" ::: "memory");
    }
    __builtin_amdgcn_s_barrier();
    asm volatile("" ::: "memory");

    const signed char* Al = &lds[p * TILE];
    const signed char* Bl = &lds[p * TILE + 64 * 64];
    i32x4 af[2], bfv[4];
#pragma unroll
    for (int mt = 0; mt < 2; ++mt)
      af[mt] = *(const i32x4*)&Al[(wr * 32 + mt * 16 + lrow) * 64 + kq];
#pragma unroll
    for (int nt = 0; nt < 4; ++nt)
      bfv[nt] = *(const i32x4*)&Bl[(wc * 64 + nt * 16 + lrow) * 64 + kq];
#pragma unroll
    for (int mt = 0; mt < 2; ++mt)
#pragma unroll
      for (int nt = 0; nt < 4; ++nt)
        acc[mt][nt] = __builtin_amdgcn_mfma_i32_16x16x64_i8(af[mt], bfv[nt], acc[mt][nt], 0, 0, 0);

    asm volatile("" ::: "memory");
    __builtin_amdgcn_s_barrier();
    p ^= 1;
  }

  // epilogue: scale by SP*SV = (1/127)*(4/127)
  const float SC = 4.0f / 16129.0f;
  const int row0 = bm * 64 + wr * 32;
  const int col0 = bn * 128 + wc * 64;
  const int rsub = (lane >> 4) << 2;
#pragma unroll
  for (int mt = 0; mt < 2; ++mt)
#pragma unroll
    for (int nt = 0; nt < 4; ++nt)
#pragma unroll
      for (int r = 0; r < 4; ++r)
        Cz[(long)(row0 + mt * 16 + rsub + r) * 512 + col0 + nt * 16 + lrow] =
            SC * (float)acc[mt][nt][r];
}

// ---------------- launch ----------------
extern "C" void kernel_launch(void* const* d_in, const int* in_sizes, int n_in,
                              void* d_out, int out_size, void* d_ws, size_t ws_size,
                              hipStream_t stream) {
  const float* x  = (const float*)d_in[0];   // [4,4096,512]
  const float* Wq = (const float*)d_in[1];   // [512,512]
  const float* bq = (const float*)d_in[2];   // [512]
  const float* Wv = (const float*)d_in[3];   // [512,512]
  const float* bv = (const float*)d_in[4];   // [512]
  float* out = (float*)d_out;                // [4,4096,512] f32

  // workspace carve (~109 MB)
  char* wsb = (char*)d_ws;
  u16* xb  = (u16*)wsb;                                   // [16384][512] bf16  32 MB
  signed char* qb8 = (signed char*)(wsb + 33554432);      // [16384][512] i8     8 MB
  signed char* vT8 = (signed char*)(wsb + 41943040);      // [512][16384] i8     8 MB
  u16* wqb = (u16*)(wsb + 50331648);                      // [512][512] bf16
  u16* wvb = (u16*)(wsb + 50855936);                      // [512][512] bf16
  u8*  P8  = (u8*)(wsb + 51380224);                       // [4][4096][4096] u8 64 MB

  conv_kernel<<<8704, 256, 0, stream>>>(x, Wq, Wv, xb, wqb, wvb);

  // q[n][e] = sum_d xb[n][d]*Wq[e][d] + bq[e] -> i8 (scale 127/4)
  gemm_nt<5, 128, 128, 4, 4, 128><<<512, 256, 0, stream>>>(xb, 512, wqb, 512,
                                                           qb8, 512, bq, 512);
  // vT[e][n] = sum_d Wv[e][d]*xb[n][d] + bv[e] -> i8 (scale 127/4)
  gemm_nt<4, 128, 128, 4, 128, 4><<<512, 256, 0, stream>>>(wvb, 512, xb, 512,
                                                           vT8, 16384, bv, 512);

  // P = round(127*sigmoid((4/127)^2 * q8 q8^T / sqrt(512))) u8, symmetric
  gemm_sym_sig_i8<32><<<4 * 528, 256, 0, stream>>>(qb8, (long)4096 * 512,
                                                   P8, (long)4096 * 4096);

  // O = (1/127)*(4/127) * P @ v
  gemm_pv_i8<<<1024, 256, 0, stream>>>((const signed char*)P8, vT8, out, 4096);
}

// Round 11
// 115.246 us; speedup vs baseline: 1.2878x; 1.2878x over previous
//
#include <hip/hip_runtime.h>
#include <hip/hip_bf16.h>
#include <stdint.h>

#define DEV __device__ __forceinline__

typedef unsigned short u16;
typedef unsigned char u8;
typedef __attribute__((ext_vector_type(8))) short bf16x8;        // 8 bf16 MFMA A/B frag
typedef __attribute__((ext_vector_type(4))) float f32x4;         // MFMA C/D frag
typedef __attribute__((ext_vector_type(4))) int i32x4;           // i8 MFMA frag / acc

DEV u16 bf(float v) {
  __hip_bfloat16 h = __float2bfloat16(v);
  union { __hip_bfloat16 h; u16 u; } x; x.h = h;
  return x.u;
}

// sigmoid(v/sqrt(512)) = 1/(1+exp2(v * -log2(e)/sqrt(512)))
DEV float sigmoid_s(float v) {
  float e = __builtin_amdgcn_exp2f(v * -0.0637587143f);
  return __builtin_amdgcn_rcpf(1.0f + e);
}

DEV signed char qi8(float v) {
  float t = fminf(fmaxf(v * 31.75f, -127.f), 127.f);   // scale 127/4
  return (signed char)(int)rintf(t);
}

DEV void gld_lds(const void* g, void* l) {
  __builtin_amdgcn_global_load_lds(
      (const __attribute__((address_space(1))) uint32_t*)g,
      (__attribute__((address_space(3))) uint32_t*)l, 16, 0, 0);
}

// ---------------- f32 -> bf16 conversion (x, Wq, Wv) ----------------
__global__ void conv_kernel(const float* __restrict__ x,
                            const float* __restrict__ Wq,
                            const float* __restrict__ Wv,
                            u16* __restrict__ xb,
                            u16* __restrict__ wqb,
                            u16* __restrict__ wvb) {
  const int NX4 = (16384 * 512) / 4;
  const int NW4 = (512 * 512) / 4;
  int i = blockIdx.x * blockDim.x + threadIdx.x;
  const float4* src; u16* dst; int off;
  if (i < NX4)            { src = (const float4*)x;  dst = xb;  off = i; }
  else if (i < NX4 + NW4) { src = (const float4*)Wq; dst = wqb; off = i - NX4; }
  else                    { src = (const float4*)Wv; dst = wvb; off = i - NX4 - NW4; }
  float4 f = src[off];
  ushort4 o = make_ushort4(bf(f.x), bf(f.y), bf(f.z), bf(f.w));
  ((ushort4*)dst)[off] = o;
}

// ---------------- fused projection GEMM: [q | v] in one pass ---------------
// C[m][n] = sum_k xb[m][k] * W[n][k], W = [Wq ; Wv] (N=1024). bf16 MFMA,
// 2-phase dbuf, counted vmcnt. bn<4 -> q half: qb8[row][col]=qi8(acc+bq[col]).
// bn>=4 -> v half: vT8[e][row..row+3] packed u32, e=col-512, +bv[e].
__global__ __launch_bounds__(256, 2)
void gemm_proj(const u16* __restrict__ xb,
               const u16* __restrict__ wqb,
               const u16* __restrict__ wvb,
               const float* __restrict__ bq,
               const float* __restrict__ bv,
               signed char* __restrict__ qb8,
               signed char* __restrict__ vT8) {
  constexpr int BK = 64, NBN = 8, NBM = 128;
  constexpr int TILE = 256 * 64;            // u16 per buffer
  __shared__ u16 lds[2 * TILE];             // 64 KB

  const int tid  = threadIdx.x;
  const int lane = tid & 63;
  const int w    = tid >> 6;
  const int wr   = w >> 1, wc = w & 1;

  const int nwg = (int)gridDim.x;           // 1024
  const int id  = blockIdx.x;
  const int swz = (id & 7) * (nwg >> 3) + (id >> 3);
  const int bn  = swz % NBN;
  const int bm  = (swz / NBN) % NBM;

  const u16* A = xb + (long)bm * 128 * 512;
  const u16* B = (bn < 4) ? wqb + (long)bn * 128 * 512
                          : wvb + (long)(bn - 4) * 128 * 512;

  const int lrow = lane & 15;
  const int rx   = lane & 7;
  const int srow = lane >> 3;
  const int scol = ((lane & 7) ^ srow) << 3;

  const u16* srcs[8];
#pragma unroll
  for (int c = 0; c < 8; ++c) {
    int row = (w * 8 + c) * 8 + srow;       // 0..255 (A | B)
    srcs[c] = (row < 128) ? A + (long)row * 512 + scol
                          : B + (long)(row - 128) * 512 + scol;
  }

  f32x4 acc[4][4] = {};

#pragma unroll
  for (int c = 0; c < 8; ++c)
    gld_lds(srcs[c], &lds[(w * 8 + c) * 512]);

  int p = 0;
  for (int kt = 0; kt < 8; ++kt) {
    if (kt + 1 < 8) {
#pragma unroll
      for (int c = 0; c < 8; ++c)
        gld_lds(srcs[c] + (kt + 1) * BK, &lds[(p ^ 1) * TILE + (w * 8 + c) * 512]);
      asm volatile("s_waitcnt vmcnt(8)" ::: "memory");
    } else {
      asm volatile("s_waitcnt vmcnt(0)" ::: "memory");
    }
    __builtin_amdgcn_s_barrier();
    asm volatile("" ::: "memory");

    const u16* Alds = &lds[p * TILE];
    const u16* Blds = &lds[p * TILE + 128 * 64];
#pragma unroll
    for (int ks = 0; ks < 2; ++ks) {
      const int sl = ((ks * 4 + (lane >> 4)) ^ rx) << 3;
      bf16x8 af[4], bfr[4];
#pragma unroll
      for (int t = 0; t < 4; ++t) {
        af[t]  = *(const bf16x8*)&Alds[(wr * 64 + t * 16 + lrow) * BK + sl];
        bfr[t] = *(const bf16x8*)&Blds[(wc * 64 + t * 16 + lrow) * BK + sl];
      }
#pragma unroll
      for (int mt = 0; mt < 4; ++mt)
#pragma unroll
        for (int nt = 0; nt < 4; ++nt)
          acc[mt][nt] = __builtin_amdgcn_mfma_f32_16x16x32_bf16(af[mt], bfr[nt], acc[mt][nt], 0, 0, 0);
    }

    asm volatile("" ::: "memory");
    __builtin_amdgcn_s_barrier();
    p ^= 1;
  }

  const int row0 = bm * 128 + wr * 64;
  const int rsub = (lane >> 4) << 2;

  if (bn < 4) {   // q half: row-major i8, bias per col
#pragma unroll
    for (int mt = 0; mt < 4; ++mt)
#pragma unroll
      for (int nt = 0; nt < 4; ++nt) {
        int col = bn * 128 + wc * 64 + nt * 16 + lrow;
        float b = bq[col];
#pragma unroll
        for (int r = 0; r < 4; ++r)
          qb8[(long)(row0 + mt * 16 + rsub + r) * 512 + col] = qi8(acc[mt][nt][r] + b);
      }
  } else {        // v half: transposed packed store into vT8[e][m]
#pragma unroll
    for (int mt = 0; mt < 4; ++mt)
#pragma unroll
      for (int nt = 0; nt < 4; ++nt) {
        int e = (bn - 4) * 128 + wc * 64 + nt * 16 + lrow;
        float b = bv[e];
        int rowb = row0 + mt * 16 + rsub;
        uint32_t pk = ((uint32_t)(u8)qi8(acc[mt][nt][0] + b)) |
                      ((uint32_t)(u8)qi8(acc[mt][nt][1] + b) << 8) |
                      ((uint32_t)(u8)qi8(acc[mt][nt][2] + b) << 16) |
                      ((uint32_t)(u8)qi8(acc[mt][nt][3] + b) << 24);
        *(uint32_t*)&vT8[(long)e * 16384 + rowb] = pk;
      }
  }
}

// ---------------- symmetric sigmoid(QQ^T) i8 GEMM -> u8 P, bn>=bm ----------
// 32 KB single-buffered staging, 4 blocks/CU. Epilogue: dequant -> sigmoid
// -> u8, LDS bounce (144 B stride), dual-orientation store for off-diagonal.
template <int NB>
__global__ __launch_bounds__(256, 4)
void gemm_sym_sig_i8(const signed char* __restrict__ Q, long sQz,
                     u8* __restrict__ P, long sPz) {
  constexpr int TRI  = NB * (NB + 1) / 2;
  constexpr int LSTR = 144;                 // bounce byte stride (multiple of 16)
  __shared__ u8 lds[256 * 128];             // 32 KB staging; bounce overlays 128*144

  const int tid  = threadIdx.x;
  const int lane = tid & 63;
  const int w    = tid >> 6;
  const int wr   = w >> 1, wc = w & 1;

  const int nwg = (int)gridDim.x;
  const int id  = blockIdx.x;
  const int swz = (id & 7) * (nwg >> 3) + (id >> 3);
  const int z   = swz / TRI;
  int rem = swz % TRI;
  int bm = 0;
  while (rem >= NB - bm) { rem -= NB - bm; ++bm; }
  const int bn = bm + rem;

  const signed char* Qz = Q + (long)z * sQz;

  const int lrow = lane & 15;
  const int rx   = lane & 7;
  const int srow = lane >> 3;                     // row within 8-row chunk
  const int scol = ((lane & 7) ^ srow) << 4;      // pre-swizzled 16B slot (of 8)

  const signed char* srcs[8];
#pragma unroll
  for (int c = 0; c < 8; ++c) {
    int row = (w * 8 + c) * 8 + srow;             // 0..255
    srcs[c] = (row < 128)
        ? Qz + (long)(bm * 128 + row) * 512 + scol
        : Qz + (long)(bn * 128 + (row - 128)) * 512 + scol;
  }

  i32x4 acc[4][4] = {};

  for (int kt = 0; kt < 4; ++kt) {                // BK = 128 bytes
#pragma unroll
    for (int c = 0; c < 8; ++c)
      gld_lds(srcs[c] + kt * 128, &lds[(w * 8 + c) * 1024]);
    __syncthreads();

#pragma unroll
    for (int ks = 0; ks < 2; ++ks) {              // two 64B k-slices
      const int sl = ((ks * 4 + (lane >> 4)) ^ rx) << 4;
      i32x4 af[4], bfv[4];
#pragma unroll
      for (int t = 0; t < 4; ++t) {
        af[t]  = *(const i32x4*)&lds[(wr * 64 + t * 16 + lrow) * 128 + sl];
        bfv[t] = *(const i32x4*)&lds[128 * 128 + (wc * 64 + t * 16 + lrow) * 128 + sl];
      }
#pragma unroll
      for (int mt = 0; mt < 4; ++mt)
#pragma unroll
        for (int nt = 0; nt < 4; ++nt)
          acc[mt][nt] = __builtin_amdgcn_mfma_i32_16x16x64_i8(af[mt], bfv[nt], acc[mt][nt], 0, 0, 0);
    }
    __syncthreads();
  }

  u8* Pz = P + (long)z * sPz;
  const int rsub = (lane >> 4) << 2;
  const bool offdiag = (bn != bm);

  // dequant (4/127)^2 -> sigmoid -> u8 0..127
  u8 sb[4][4][4];
#pragma unroll
  for (int mt = 0; mt < 4; ++mt)
#pragma unroll
    for (int nt = 0; nt < 4; ++nt)
#pragma unroll
      for (int r = 0; r < 4; ++r) {
        float v = (float)acc[mt][nt][r] * 9.91941e-4f;
        sb[mt][nt][r] = (u8)(int)(sigmoid_s(v) * 127.f + 0.5f);
      }

  const int rl = wr * 64 + rsub;    // local row base (+mt*16, +r)
  const int cl = wc * 64 + lrow;    // local col base (+nt*16)
  const int coloff = (tid & 7) * 16;
  const int rdrow  = tid >> 3;      // 0..31

  // pass 1: normal orientation bounce -> dense 16B stores
#pragma unroll
  for (int mt = 0; mt < 4; ++mt)
#pragma unroll
    for (int nt = 0; nt < 4; ++nt)
#pragma unroll
      for (int r = 0; r < 4; ++r)
        lds[(rl + mt * 16 + r) * LSTR + cl + nt * 16] = sb[mt][nt][r];
  __syncthreads();
#pragma unroll
  for (int j = 0; j < 4; ++j) {
    int row = j * 32 + rdrow;
    uint4 v = *(const uint4*)&lds[row * LSTR + coloff];
    *(uint4*)&Pz[(long)(bm * 128 + row) * 4096 + bn * 128 + coloff] = v;
  }

  if (offdiag) {
    __syncthreads();   // WAR: pass-1 reads done before overwrite
    // pass 2: transposed; frag's 4 consecutive rows -> 4 bytes -> one u32
#pragma unroll
    for (int mt = 0; mt < 4; ++mt)
#pragma unroll
      for (int nt = 0; nt < 4; ++nt) {
        uint32_t pk = (uint32_t)sb[mt][nt][0] | ((uint32_t)sb[mt][nt][1] << 8) |
                      ((uint32_t)sb[mt][nt][2] << 16) | ((uint32_t)sb[mt][nt][3] << 24);
        *(uint32_t*)&lds[(cl + nt * 16) * LSTR + rl + mt * 16] = pk;
      }
    __syncthreads();
#pragma unroll
    for (int j = 0; j < 4; ++j) {
      int row = j * 32 + rdrow;
      uint4 v = *(const uint4*)&lds[row * LSTR + coloff];
      *(uint4*)&Pz[(long)(bn * 128 + row) * 4096 + bm * 128 + coloff] = v;
    }
  }
}

// ---------------- O = (SP*SV) * P_u8 @ vT_i8^T, i8 MFMA ------------------
// r9 geometry (128x128, 4 waves, wave tile 64x64 — the proven winner) with
// BK=128 B: half the K-iterations/barriers, 32-MFMA bursts. 8-slot XOR
// swizzle identical to gemm_sym_sig_i8 (measured ~free). LDS 64 KB dbuf.
__global__ __launch_bounds__(256, 2)
void gemm_pv_i8(const signed char* __restrict__ A,   // P [4*4096][4096] (u8 vals)
                const signed char* __restrict__ B,   // vT_i8 [512][16384]
                float* __restrict__ C) {             // out [4*4096][512]
  constexpr int NBN = 4, NBM = 32;
  constexpr int TILE = 256 * 128;         // bytes per buffer (32 KB)
  __shared__ signed char lds[2 * TILE];   // 64 KB

  const int tid  = threadIdx.x;
  const int lane = tid & 63;
  const int w    = tid >> 6;              // 0..3
  const int wr   = w >> 1, wc = w & 1;

  const int nwg = (int)gridDim.x;
  const int id  = blockIdx.x;
  const int swz = (id & 7) * (nwg >> 3) + (id >> 3);
  const int bn  = swz % NBN;
  const int t0  = swz / NBN;
  const int bm  = t0 % NBM;
  const int z   = t0 / NBM;

  const signed char* Az = A + (long)z * 4096 * 4096;
  const signed char* Bz = B + (long)z * 4096;
  float* Cz = C + (long)z * 4096 * 512;

  const int lrow = lane & 15;
  const int rx   = lane & 7;
  const int srow = lane >> 3;                     // row within 8-row chunk
  const int scol = ((lane & 7) ^ srow) << 4;      // pre-swizzled 16B slot (of 8)

  // staging: 32 chunks x 1KB (8 rows x 128 B); 8 chunks/wave
  const signed char* srcs[8];
#pragma unroll
  for (int c = 0; c < 8; ++c) {
    int row = (w * 8 + c) * 8 + srow;             // 0..255 (A:0-127 | B:128-255)
    srcs[c] = (row < 128)
        ? Az + (long)(bm * 128 + row) * 4096 + scol
        : Bz + (long)(bn * 128 + (row - 128)) * 16384 + scol;
  }

  i32x4 acc[4][4] = {};

  const int nk = 32;                              // 4096 / 128
#pragma unroll
  for (int c = 0; c < 8; ++c)
    gld_lds(srcs[c], &lds[(w * 8 + c) * 1024]);

  int p = 0;
  for (int kt = 0; kt < nk; ++kt) {
    if (kt + 1 < nk) {
#pragma unroll
      for (int c = 0; c < 8; ++c)
        gld_lds(srcs[c] + (kt + 1) * 128, &lds[(p ^ 1) * TILE + (w * 8 + c) * 1024]);
      asm volatile("s_waitcnt vmcnt(8)" ::: "memory");
    } else {
      asm volatile("s_waitcnt vmcnt(0)" ::: "memory");
    }
    __builtin_amdgcn_s_barrier();
    asm volatile("" ::: "memory");

    const signed char* Al = &lds[p * TILE];
    const signed char* Bl = &lds[p * TILE + 128 * 128];
#pragma unroll
    for (int ks = 0; ks < 2; ++ks) {              // two 64B k-slices
      const int sl = ((ks * 4 + (lane >> 4)) ^ rx) << 4;
      i32x4 af[4], bfv[4];
#pragma unroll
      for (int t = 0; t < 4; ++t) {
        af[t]  = *(const i32x4*)&Al[(wr * 64 + t * 16 + lrow) * 128 + sl];
        bfv[t] = *(const i32x4*)&Bl[(wc * 64 + t * 16 + lrow) * 128 + sl];
      }
#pragma unroll
      for (int mt = 0; mt < 4; ++mt)
#pragma unroll
        for (int nt = 0; nt < 4; ++nt)
          acc[mt][nt] = __builtin_amdgcn_mfma_i32_16x16x64_i8(af[mt], bfv[nt], acc[mt][nt], 0, 0, 0);
    }

    asm volatile("" ::: "memory");
    __builtin_amdgcn_s_barrier();
    p ^= 1;
  }

  // epilogue: scale by SP*SV = (1/127)*(4/127)
  const float SC = 4.0f / 16129.0f;
  const int row0 = bm * 128 + wr * 64;
  const int col0 = bn * 128 + wc * 64;
  const int rsub = (lane >> 4) << 2;
#pragma unroll
  for (int mt = 0; mt < 4; ++mt)
#pragma unroll
    for (int nt = 0; nt < 4; ++nt)
#pragma unroll
      for (int r = 0; r < 4; ++r)
        Cz[(long)(row0 + mt * 16 + rsub + r) * 512 + col0 + nt * 16 + lrow] =
            SC * (float)acc[mt][nt][r];
}

// ---------------- launch ----------------
extern "C" void kernel_launch(void* const* d_in, const int* in_sizes, int n_in,
                              void* d_out, int out_size, void* d_ws, size_t ws_size,
                              hipStream_t stream) {
  const float* x  = (const float*)d_in[0];   // [4,4096,512]
  const float* Wq = (const float*)d_in[1];   // [512,512]
  const float* bq = (const float*)d_in[2];   // [512]
  const float* Wv = (const float*)d_in[3];   // [512,512]
  const float* bv = (const float*)d_in[4];   // [512]
  float* out = (float*)d_out;                // [4,4096,512] f32

  // workspace carve (~109 MB)
  char* wsb = (char*)d_ws;
  u16* xb  = (u16*)wsb;                                   // [16384][512] bf16  32 MB
  signed char* qb8 = (signed char*)(wsb + 33554432);      // [16384][512] i8     8 MB
  signed char* vT8 = (signed char*)(wsb + 41943040);      // [512][16384] i8     8 MB
  u16* wqb = (u16*)(wsb + 50331648);                      // [512][512] bf16
  u16* wvb = (u16*)(wsb + 50855936);                      // [512][512] bf16
  u8*  P8  = (u8*)(wsb + 51380224);                       // [4][4096][4096] u8 64 MB

  conv_kernel<<<8704, 256, 0, stream>>>(x, Wq, Wv, xb, wqb, wvb);

  // fused: q8 = qi8(xb Wq^T + bq), vT8 = qi8(xb Wv^T + bv)^T  (one pass over xb)
  gemm_proj<<<1024, 256, 0, stream>>>(xb, wqb, wvb, bq, bv, qb8, vT8);

  // P = round(127*sigmoid((4/127)^2 * q8 q8^T / sqrt(512))) u8, symmetric
  gemm_sym_sig_i8<32><<<4 * 528, 256, 0, stream>>>(qb8, (long)4096 * 512,
                                                   P8, (long)4096 * 4096);

  // O = (1/127)*(4/127) * P @ v
  gemm_pv_i8<<<512, 256, 0, stream>>>((const signed char*)P8, vT8, out);
}

// Round 13
// 115.120 us; speedup vs baseline: 1.2892x; 1.0011x over previous
//
#include <hip/hip_runtime.h>
#include <hip/hip_bf16.h>
#include <stdint.h>

#define DEV __device__ __forceinline__

typedef unsigned short u16;
typedef unsigned char u8;
typedef __attribute__((ext_vector_type(8))) short bf16x8;        // 8 bf16 MFMA A/B frag
typedef __attribute__((ext_vector_type(4))) float f32x4;         // MFMA C/D frag
typedef __attribute__((ext_vector_type(4))) int i32x4;           // i8 MFMA frag / acc

DEV u16 bf(float v) {
  __hip_bfloat16 h = __float2bfloat16(v);
  union { __hip_bfloat16 h; u16 u; } x; x.h = h;
  return x.u;
}

// sigmoid(v/sqrt(512)) = 1/(1+exp2(v * -log2(e)/sqrt(512)))
DEV float sigmoid_s(float v) {
  float e = __builtin_amdgcn_exp2f(v * -0.0637587143f);
  return __builtin_amdgcn_rcpf(1.0f + e);
}

DEV signed char qi8(float v) {
  float t = fminf(fmaxf(v * 31.75f, -127.f), 127.f);   // scale 127/4
  return (signed char)(int)rintf(t);
}

DEV void gld_lds(const void* g, void* l) {
  __builtin_amdgcn_global_load_lds(
      (const __attribute__((address_space(1))) uint32_t*)g,
      (__attribute__((address_space(3))) uint32_t*)l, 16, 0, 0);
}

// ---------------- f32 -> bf16 conversion (x, Wq, Wv) ----------------
__global__ void conv_kernel(const float* __restrict__ x,
                            const float* __restrict__ Wq,
                            const float* __restrict__ Wv,
                            u16* __restrict__ xb,
                            u16* __restrict__ wqb,
                            u16* __restrict__ wvb) {
  const int NX4 = (16384 * 512) / 4;
  const int NW4 = (512 * 512) / 4;
  int i = blockIdx.x * blockDim.x + threadIdx.x;
  const float4* src; u16* dst; int off;
  if (i < NX4)            { src = (const float4*)x;  dst = xb;  off = i; }
  else if (i < NX4 + NW4) { src = (const float4*)Wq; dst = wqb; off = i - NX4; }
  else                    { src = (const float4*)Wv; dst = wvb; off = i - NX4 - NW4; }
  float4 f = src[off];
  ushort4 o = make_ushort4(bf(f.x), bf(f.y), bf(f.z), bf(f.w));
  ((ushort4*)dst)[off] = o;
}

// ---------------- fused projection GEMM: [q | v] in one pass ---------------
__global__ __launch_bounds__(256, 2)
void gemm_proj(const u16* __restrict__ xb,
               const u16* __restrict__ wqb,
               const u16* __restrict__ wvb,
               const float* __restrict__ bq,
               const float* __restrict__ bv,
               signed char* __restrict__ qb8,
               signed char* __restrict__ vT8) {
  constexpr int BK = 64, NBN = 8, NBM = 128;
  constexpr int TILE = 256 * 64;            // u16 per buffer
  __shared__ u16 lds[2 * TILE];             // 64 KB

  const int tid  = threadIdx.x;
  const int lane = tid & 63;
  const int w    = tid >> 6;
  const int wr   = w >> 1, wc = w & 1;

  const int nwg = (int)gridDim.x;           // 1024
  const int id  = blockIdx.x;
  const int swz = (id & 7) * (nwg >> 3) + (id >> 3);
  const int bn  = swz % NBN;
  const int bm  = (swz / NBN) % NBM;

  const u16* A = xb + (long)bm * 128 * 512;
  const u16* B = (bn < 4) ? wqb + (long)bn * 128 * 512
                          : wvb + (long)(bn - 4) * 128 * 512;

  const int lrow = lane & 15;
  const int rx   = lane & 7;
  const int srow = lane >> 3;
  const int scol = ((lane & 7) ^ srow) << 3;

  const u16* srcs[8];
#pragma unroll
  for (int c = 0; c < 8; ++c) {
    int row = (w * 8 + c) * 8 + srow;       // 0..255 (A | B)
    srcs[c] = (row < 128) ? A + (long)row * 512 + scol
                          : B + (long)(row - 128) * 512 + scol;
  }

  f32x4 acc[4][4] = {};

#pragma unroll
  for (int c = 0; c < 8; ++c)
    gld_lds(srcs[c], &lds[(w * 8 + c) * 512]);

  int p = 0;
  for (int kt = 0; kt < 8; ++kt) {
    if (kt + 1 < 8) {
#pragma unroll
      for (int c = 0; c < 8; ++c)
        gld_lds(srcs[c] + (kt + 1) * BK, &lds[(p ^ 1) * TILE + (w * 8 + c) * 512]);
      asm volatile("s_waitcnt vmcnt(8)" ::: "memory");
    } else {
      asm volatile("s_waitcnt vmcnt(0)" ::: "memory");
    }
    __builtin_amdgcn_s_barrier();
    asm volatile("" ::: "memory");

    const u16* Alds = &lds[p * TILE];
    const u16* Blds = &lds[p * TILE + 128 * 64];
#pragma unroll
    for (int ks = 0; ks < 2; ++ks) {
      const int sl = ((ks * 4 + (lane >> 4)) ^ rx) << 3;
      bf16x8 af[4], bfr[4];
#pragma unroll
      for (int t = 0; t < 4; ++t) {
        af[t]  = *(const bf16x8*)&Alds[(wr * 64 + t * 16 + lrow) * BK + sl];
        bfr[t] = *(const bf16x8*)&Blds[(wc * 64 + t * 16 + lrow) * BK + sl];
      }
#pragma unroll
      for (int mt = 0; mt < 4; ++mt)
#pragma unroll
        for (int nt = 0; nt < 4; ++nt)
          acc[mt][nt] = __builtin_amdgcn_mfma_f32_16x16x32_bf16(af[mt], bfr[nt], acc[mt][nt], 0, 0, 0);
    }

    asm volatile("" ::: "memory");
    __builtin_amdgcn_s_barrier();
    p ^= 1;
  }

  const int row0 = bm * 128 + wr * 64;
  const int rsub = (lane >> 4) << 2;

  if (bn < 4) {   // q half: row-major i8, bias per col
#pragma unroll
    for (int mt = 0; mt < 4; ++mt)
#pragma unroll
      for (int nt = 0; nt < 4; ++nt) {
        int col = bn * 128 + wc * 64 + nt * 16 + lrow;
        float b = bq[col];
#pragma unroll
        for (int r = 0; r < 4; ++r)
          qb8[(long)(row0 + mt * 16 + rsub + r) * 512 + col] = qi8(acc[mt][nt][r] + b);
      }
  } else {        // v half: transposed packed store into vT8[e][m]
#pragma unroll
    for (int mt = 0; mt < 4; ++mt)
#pragma unroll
      for (int nt = 0; nt < 4; ++nt) {
        int e = (bn - 4) * 128 + wc * 64 + nt * 16 + lrow;
        float b = bv[e];
        int rowb = row0 + mt * 16 + rsub;
        uint32_t pk = ((uint32_t)(u8)qi8(acc[mt][nt][0] + b)) |
                      ((uint32_t)(u8)qi8(acc[mt][nt][1] + b) << 8) |
                      ((uint32_t)(u8)qi8(acc[mt][nt][2] + b) << 16) |
                      ((uint32_t)(u8)qi8(acc[mt][nt][3] + b) << 24);
        *(uint32_t*)&vT8[(long)e * 16384 + rowb] = pk;
      }
  }
}

// ---------------- symmetric sigmoid(QQ^T) i8 GEMM -> u8 P ------------------
// 256(M)x128(N) macro-tile = 2 stacked 128-tiles; 8 waves (4x2), wave tile
// 64x64. Triangle over 128-units: macro (m,n) exists iff n >= 2m; per
// 128-row half h (global row-block gr = 2m+h): normal store iff n >= gr;
// transposed dual-store iff n > gr. Staging 48 KB single-buffered, BK=128 B.
__global__ __launch_bounds__(512, 4)
void gemm_sym_sig_i8(const signed char* __restrict__ Q, long sQz,
                     u8* __restrict__ P, long sPz) {
  __shared__ u8 lds[49152];                 // 48 KB: staging 384x128 | bounce 256x144

  const int tid  = threadIdx.x;
  const int lane = tid & 63;
  const int w    = tid >> 6;                // 0..7
  const int wr   = w >> 1, wc = w & 1;      // 4 x 2

  const int nwg = (int)gridDim.x;           // 1088
  const int id  = blockIdx.x;
  const int swz = (id & 7) * (nwg >> 3) + (id >> 3);
  const int z   = swz / 272;
  int rem = swz % 272;
  int m = 0;
  while (rem >= 32 - 2 * m) { rem -= 32 - 2 * m; ++m; }
  const int n = 2 * m + rem;                // col block (128-units), n >= 2m

  const int R0 = m * 256;                   // global row base
  const int C0 = n * 128;                   // global col base
  const signed char* Qz = Q + (long)z * sQz;

  const int lrow = lane & 15;
  const int rx   = lane & 7;
  const int srow = lane >> 3;                     // row within 8-row chunk
  const int scol = ((lane & 7) ^ srow) << 4;      // pre-swizzled 16B slot (of 8)

  // staging: 48 chunks x 1KB (8 rows x 128 B); 6 chunks/wave
  const signed char* srcs[6];
#pragma unroll
  for (int c = 0; c < 6; ++c) {
    int row = (w * 6 + c) * 8 + srow;             // 0..383 (A:0-255 | B:256-383)
    srcs[c] = (row < 256)
        ? Qz + (long)(R0 + row) * 512 + scol
        : Qz + (long)(C0 + (row - 256)) * 512 + scol;
  }

  i32x4 acc[4][4] = {};

  for (int kt = 0; kt < 4; ++kt) {                // BK = 128 bytes
#pragma unroll
    for (int c = 0; c < 6; ++c)
      gld_lds(srcs[c] + kt * 128, &lds[(w * 6 + c) * 1024]);
    __syncthreads();

#pragma unroll
    for (int ks = 0; ks < 2; ++ks) {              // two 64B k-slices
      const int sl = ((ks * 4 + (lane >> 4)) ^ rx) << 4;
      i32x4 af[4], bfv[4];
#pragma unroll
      for (int t = 0; t < 4; ++t) {
        af[t]  = *(const i32x4*)&lds[(wr * 64 + t * 16 + lrow) * 128 + sl];
        bfv[t] = *(const i32x4*)&lds[256 * 128 + (wc * 64 + t * 16 + lrow) * 128 + sl];
      }
      __builtin_amdgcn_s_setprio(1);
#pragma unroll
      for (int mt = 0; mt < 4; ++mt)
#pragma unroll
        for (int nt = 0; nt < 4; ++nt)
          acc[mt][nt] = __builtin_amdgcn_mfma_i32_16x16x64_i8(af[mt], bfv[nt], acc[mt][nt], 0, 0, 0);
      __builtin_amdgcn_s_setprio(0);
    }
    __syncthreads();
  }

  u8* Pz = P + (long)z * sPz;
  const int rsub = (lane >> 4) << 2;
  const int rl = wr * 64 + rsub;            // local row base (+mt*16, +r)
  const int cl = wc * 64 + lrow;            // local col base (+nt*16)

  // dequant (4/127)^2 -> sigmoid -> u8, packed 4 rows per u32
  uint32_t sbp[4][4];
#pragma unroll
  for (int mt = 0; mt < 4; ++mt)
#pragma unroll
    for (int nt = 0; nt < 4; ++nt) {
      uint32_t pk = 0;
#pragma unroll
      for (int r = 0; r < 4; ++r) {
        float v = (float)acc[mt][nt][r] * 9.91941e-4f;
        pk |= (uint32_t)(u8)(int)(sigmoid_s(v) * 127.f + 0.5f) << (8 * r);
      }
      sbp[mt][nt] = pk;
    }

  const int sslot = tid & 7;               // 16B slot within 128B row
  const int srow2 = tid >> 3;              // 0..63

  // pass 1: normal orientation bounce (256x144) -> dense 16B row stores
#pragma unroll
  for (int mt = 0; mt < 4; ++mt)
#pragma unroll
    for (int nt = 0; nt < 4; ++nt) {
      uint32_t pk = sbp[mt][nt];
#pragma unroll
      for (int r = 0; r < 4; ++r)
        lds[(rl + mt * 16 + r) * 144 + cl + nt * 16] = (u8)(pk >> (8 * r));
    }
  __syncthreads();
#pragma unroll
  for (int j = 0; j < 4; ++j) {            // rows j*64 .. j*64+63; half = j>>1
    int row = j * 64 + srow2;
    if (j < 2 || n > 2 * m) {              // store iff n >= 2m + half
      uint4 v = *(const uint4*)&lds[row * 144 + sslot * 16];
      *(uint4*)&Pz[(long)(R0 + row) * 4096 + C0 + sslot * 16] = v;
    }
  }
  __syncthreads();                         // pass-1 reads done before reuse

  // pass 2: transposed store per half h iff n > 2m + h
#pragma unroll
  for (int h = 0; h < 2; ++h) {
    if (n > 2 * m + h) {
      if ((wr >> 1) == h) {                // waves owning rows of half h
#pragma unroll
        for (int mt = 0; mt < 4; ++mt)
#pragma unroll
          for (int nt = 0; nt < 4; ++nt)
            *(uint32_t*)&lds[(cl + nt * 16) * 144 + (rl - 128 * h + mt * 16)] = sbp[mt][nt];
      }
      __syncthreads();
#pragma unroll
      for (int j = 0; j < 2; ++j) {        // 128 rows x 8 slots
        int row = j * 64 + srow2;
        uint4 v = *(const uint4*)&lds[row * 144 + sslot * 16];
        *(uint4*)&Pz[(long)(C0 + row) * 4096 + R0 + 128 * h + sslot * 16] = v;
      }
      __syncthreads();
    }
  }
}

// ---------------- O = (SP*SV) * P_u8 @ vT_i8^T, i8 MFMA, BK=128 ------------
__global__ __launch_bounds__(256, 2)
void gemm_pv_i8(const signed char* __restrict__ A,   // P [4*4096][4096] (u8 vals)
                const signed char* __restrict__ B,   // vT_i8 [512][16384]
                float* __restrict__ C) {             // out [4*4096][512]
  constexpr int NBN = 4, NBM = 32;
  constexpr int TILE = 256 * 128;         // bytes per buffer (32 KB)
  __shared__ signed char lds[2 * TILE];   // 64 KB

  const int tid  = threadIdx.x;
  const int lane = tid & 63;
  const int w    = tid >> 6;              // 0..3
  const int wr   = w >> 1, wc = w & 1;

  const int nwg = (int)gridDim.x;
  const int id  = blockIdx.x;
  const int swz = (id & 7) * (nwg >> 3) + (id >> 3);
  const int bn  = swz % NBN;
  const int t0  = swz / NBN;
  const int bm  = t0 % NBM;
  const int z   = t0 / NBM;

  const signed char* Az = A + (long)z * 4096 * 4096;
  const signed char* Bz = B + (long)z * 4096;
  float* Cz = C + (long)z * 4096 * 512;

  const int lrow = lane & 15;
  const int rx   = lane & 7;
  const int srow = lane >> 3;                     // row within 8-row chunk
  const int scol = ((lane & 7) ^ srow) << 4;      // pre-swizzled 16B slot (of 8)

  // staging: 32 chunks x 1KB (8 rows x 128 B); 8 chunks/wave
  const signed char* srcs[8];
#pragma unroll
  for (int c = 0; c < 8; ++c) {
    int row = (w * 8 + c) * 8 + srow;             // 0..255 (A:0-127 | B:128-255)
    srcs[c] = (row < 128)
        ? Az + (long)(bm * 128 + row) * 4096 + scol
        : Bz + (long)(bn * 128 + (row - 128)) * 16384 + scol;
  }

  i32x4 acc[4][4] = {};

  const int nk = 32;                              // 4096 / 128
#pragma unroll
  for (int c = 0; c < 8; ++c)
    gld_lds(srcs[c], &lds[(w * 8 + c) * 1024]);

  int p = 0;
  for (int kt = 0; kt < nk; ++kt) {
    if (kt + 1 < nk) {
#pragma unroll
      for (int c = 0; c < 8; ++c)
        gld_lds(srcs[c] + (kt + 1) * 128, &lds[(p ^ 1) * TILE + (w * 8 + c) * 1024]);
      asm volatile("s_waitcnt vmcnt(8)" ::: "memory");
    } else {
      asm volatile("s_waitcnt vmcnt(0)" ::: "memory");
    }
    __builtin_amdgcn_s_barrier();
    asm volatile("" ::: "memory");

    const signed char* Al = &lds[p * TILE];
    const signed char* Bl = &lds[p * TILE + 128 * 128];
#pragma unroll
    for (int ks = 0; ks < 2; ++ks) {              // two 64B k-slices
      const int sl = ((ks * 4 + (lane >> 4)) ^ rx) << 4;
      i32x4 af[4], bfv[4];
#pragma unroll
      for (int t = 0; t < 4; ++t) {
        af[t]  = *(const i32x4*)&Al[(wr * 64 + t * 16 + lrow) * 128 + sl];
        bfv[t] = *(const i32x4*)&Bl[(wc * 64 + t * 16 + lrow) * 128 + sl];
      }
      __builtin_amdgcn_s_setprio(1);
#pragma unroll
      for (int mt = 0; mt < 4; ++mt)
#pragma unroll
        for (int nt = 0; nt < 4; ++nt)
          acc[mt][nt] = __builtin_amdgcn_mfma_i32_16x16x64_i8(af[mt], bfv[nt], acc[mt][nt], 0, 0, 0);
      __builtin_amdgcn_s_setprio(0);
    }

    asm volatile("" ::: "memory");
    __builtin_amdgcn_s_barrier();
    p ^= 1;
  }

  // epilogue: scale by SP*SV = (1/127)*(4/127)
  const float SC = 4.0f / 16129.0f;
  const int row0 = bm * 128 + wr * 64;
  const int col0 = bn * 128 + wc * 64;
  const int rsub = (lane >> 4) << 2;
#pragma unroll
  for (int mt = 0; mt < 4; ++mt)
#pragma unroll
    for (int nt = 0; nt < 4; ++nt)
#pragma unroll
      for (int r = 0; r < 4; ++r)
        Cz[(long)(row0 + mt * 16 + rsub + r) * 512 + col0 + nt * 16 + lrow] =
            SC * (float)acc[mt][nt][r];
}

// ---------------- launch ----------------
extern "C" void kernel_launch(void* const* d_in, const int* in_sizes, int n_in,
                              void* d_out, int out_size, void* d_ws, size_t ws_size,
                              hipStream_t stream) {
  const float* x  = (const float*)d_in[0];   // [4,4096,512]
  const float* Wq = (const float*)d_in[1];   // [512,512]
  const float* bq = (const float*)d_in[2];   // [512]
  const float* Wv = (const float*)d_in[3];   // [512,512]
  const float* bv = (const float*)d_in[4];   // [512]
  float* out = (float*)d_out;                // [4,4096,512] f32

  // workspace carve (~109 MB)
  char* wsb = (char*)d_ws;
  u16* xb  = (u16*)wsb;                                   // [16384][512] bf16  32 MB
  signed char* qb8 = (signed char*)(wsb + 33554432);      // [16384][512] i8     8 MB
  signed char* vT8 = (signed char*)(wsb + 41943040);      // [512][16384] i8     8 MB
  u16* wqb = (u16*)(wsb + 50331648);                      // [512][512] bf16
  u16* wvb = (u16*)(wsb + 50855936);                      // [512][512] bf16
  u8*  P8  = (u8*)(wsb + 51380224);                       // [4][4096][4096] u8 64 MB

  conv_kernel<<<8704, 256, 0, stream>>>(x, Wq, Wv, xb, wqb, wvb);

  // fused: q8 = qi8(xb Wq^T + bq), vT8 = qi8(xb Wv^T + bv)^T
  gemm_proj<<<1024, 256, 0, stream>>>(xb, wqb, wvb, bq, bv, qb8, vT8);

  // P = round(127*sigmoid((4/127)^2 * q8 q8^T / sqrt(512))) u8, symmetric
  gemm_sym_sig_i8<<<1088, 512, 0, stream>>>(qb8, (long)4096 * 512,
                                            P8, (long)4096 * 4096);

  // O = (1/127)*(4/127) * P @ v
  gemm_pv_i8<<<512, 256, 0, stream>>>((const signed char*)P8, vT8, out);
}